// Round 1
// baseline (211.669 us; speedup 1.0000x reference)
//
#include <hip/hip_runtime.h>

// ---------------------------------------------------------------------------
// MLA attention, fp16 MFMA pipeline v10.  B=2, S=2048, D=1024, H=16, Dh=64, L=256
//
// Launches (6):
//   prep   : xh = f16(x) + Bt1=[Wq^T;Wl^T], Bt2=[Wk^T;Wv^T], Wot=Wo^T (linear)
//   GEMM1  : xh@Bt1 -> q' (0.125*(xWq+bq)) | lat          [BK=64, no occ bound]
//   GEMM2  : lat@Bt2 -> k | vt[bh][d][s]                  [BK=64]
//   attn   : v10: q-block 128 (4 waves x 32q), Ps[128][76] -> LDS 38.9 KB
//            => 4 blocks/CU (was 2), grid 1024 blocks. Softmax/PV structure
//            unchanged (fixed-shift exp, P via LDS round-trip).
//   combine: att = (O0+O1)/(l0+l1)                        [r4 verbatim]
//   GEMM3  : att@Wot -> out (f32)                         [BK=64]
//
// v10 theory: attn was occupancy-bound (Occ 18%, Mfma 22%, VALU 31%, HBM 19%).
// Ps (38 KB) capped residency at 2 blocks/CU with a 512-block grid. Halving
// the q-block halves Ps and the register arrays: LDS 58368->38912 B,
// VGPR fits launch_bounds(256,4), grid 512->1024 -> 4 blocks/CU.
//
// MFMA 16x16x32 f16 layouts (HW-verified r2/r3):
//   A-frag: lane holds A[m=lane&15][k=quad*8+j]   B-frag: Bt[n=lane&15][k..]
//   C/D:    lane reg r holds C[row=quad*4+r][col=lane&15]
// ---------------------------------------------------------------------------

typedef _Float16 half8  __attribute__((ext_vector_type(8)));
typedef _Float16 half4  __attribute__((ext_vector_type(4)));
typedef float    floatx4 __attribute__((ext_vector_type(4)));

// ---------------- prep: convert x + all weight transposes (linear) ---------
__global__ __launch_bounds__(256) void prep(
    const float* __restrict__ x,
    const float* __restrict__ Wq, const float* __restrict__ Wl,
    const float* __restrict__ Wk, const float* __restrict__ Wv,
    const float* __restrict__ Wo,
    _Float16* __restrict__ xh,
    _Float16* __restrict__ Bt1, _Float16* __restrict__ Bt2,
    _Float16* __restrict__ Wot)
{
    const int t = threadIdx.x;
    if (blockIdx.z == 5) {              // convert x: 1024 slots x 256 thr x 16
        size_t base = ((size_t)(blockIdx.y * 32 + blockIdx.x) * 256 + t) * 16;
#pragma unroll
        for (int it = 0; it < 4; ++it) {
            floatx4 v = *(const floatx4*)(x + base + it * 4);
            *(half4*)(xh + base + it * 4) = __builtin_convertvector(v, half4);
        }
        return;
    }
    const float* src; _Float16* dst; int K, N;
    switch (blockIdx.z) {
        case 0:  src = Wq; dst = Bt1;                 K = 1024; N = 1024; break;
        case 1:  src = Wl; dst = Bt1 + 1024 * 1024;   K = 1024; N = 256;  break;
        case 2:  src = Wk; dst = Bt2;                 K = 256;  N = 1024; break;
        case 3:  src = Wv; dst = Bt2 + 1024 * 256;    K = 256;  N = 1024; break;
        default: src = Wo; dst = Wot;                 K = 1024; N = 1024; break;
    }
    const int n0 = blockIdx.x * 32, k0 = blockIdx.y * 32;
    if (n0 >= N || k0 >= K) return;
    __shared__ _Float16 tile[32][33];
    const int tx = t & 31, ty = t >> 5;
#pragma unroll
    for (int i = 0; i < 4; ++i)
        tile[ty + 8 * i][tx] = (_Float16)src[(size_t)(k0 + ty + 8 * i) * N + n0 + tx];
    __syncthreads();
#pragma unroll
    for (int i = 0; i < 4; ++i)
        dst[(size_t)(n0 + ty + 8 * i) * K + k0 + tx] = tile[tx][ty + 8 * i];
}

// ---------------- fp16 MFMA GEMM, 128x64 tile, BK=64, 4 waves (64x32 each) --
// MODE 0: col<1024 -> q'=0.125*(c+bq) f16; col>=1024 -> lat f16 [*,256]
// MODE 1: col<1024 -> k f16 RM; col>=1024 -> vt[bh][d][s] via LDS transpose
// MODE 2: out f32 RM + bias
template <int MODE>
__global__ __launch_bounds__(256) void gemm_fused(
    const _Float16* __restrict__ A, const _Float16* __restrict__ Bt,
    const float* __restrict__ bias0, const float* __restrict__ bias1,
    void* __restrict__ out0, void* __restrict__ out1,
    int N, int K)
{
    __shared__ _Float16 As[128 * 64];                 // 16 KB
    __shared__ _Float16 Bs[64 * 64];                  // 8 KB
    __shared__ _Float16 Tt[(MODE == 1) ? 64 * 136 : 1];
    const int t = threadIdx.x;
    const int lane = t & 63, w = t >> 6;
    const int quad = lane >> 4, low = lane & 15;
    const int row0 = blockIdx.y * 128, col0 = blockIdx.x * 64;
    const int wm = (w >> 1) * 64, wn = (w & 1) * 32;

    floatx4 acc[4][2];
    const floatx4 z4 = {0.f, 0.f, 0.f, 0.f};
#pragma unroll
    for (int i = 0; i < 4; ++i)
#pragma unroll
        for (int j = 0; j < 2; ++j) acc[i][j] = z4;

    // BK=64 staging: one inst = 8 rows x 8 slots of 16B. Lane (srow8, sslot).
    // Lane fetches global group sslot^(row&7) so LDS slot s holds group
    // s^(row&7): frag readers un-permute with the same XOR.
    const int srow8 = lane >> 3;
    const int sslot = lane & 7;
    const int fswz = (low & 7);          // frag-read XOR term

    for (int k0 = 0; k0 < K; k0 += 64) {
        __syncthreads();
#pragma unroll
        for (int c = 0; c < 4; ++c) {      // A: 16 chunks of 8 rows, 4 per wave
            const int chunk = w * 4 + c;
            const int row = chunk * 8 + srow8;
            const int g = sslot ^ (row & 7);
            const _Float16* gp = A + (size_t)(row0 + row) * K + k0 + g * 8;
            __builtin_amdgcn_global_load_lds(
                (const __attribute__((address_space(1))) void*)gp,
                (__attribute__((address_space(3))) void*)(As + chunk * 512), 16, 0, 0);
        }
#pragma unroll
        for (int c = 0; c < 2; ++c) {      // B: 8 chunks of 8 rows, 2 per wave
            const int chunk = w * 2 + c;
            const int row = chunk * 8 + srow8;
            const int g = sslot ^ (row & 7);
            const _Float16* gp = Bt + (size_t)(col0 + row) * K + k0 + g * 8;
            __builtin_amdgcn_global_load_lds(
                (const __attribute__((address_space(1))) void*)gp,
                (__attribute__((address_space(3))) void*)(Bs + chunk * 512), 16, 0, 0);
        }
        __syncthreads();

#pragma unroll
        for (int kk = 0; kk < 2; ++kk) {
            const int slot = ((4 * kk + quad) ^ fswz) << 3;
            half8 a[4], b[2];
#pragma unroll
            for (int i = 0; i < 4; ++i)
                a[i] = *(const half8*)(As + (wm + i * 16 + low) * 64 + slot);
#pragma unroll
            for (int j = 0; j < 2; ++j)
                b[j] = *(const half8*)(Bs + (wn + j * 16 + low) * 64 + slot);
#pragma unroll
            for (int i = 0; i < 4; ++i)
#pragma unroll
                for (int j = 0; j < 2; ++j)
                    acc[i][j] = __builtin_amdgcn_mfma_f32_16x16x32_f16(a[i], b[j], acc[i][j], 0, 0, 0);
        }
    }

    if (MODE == 1 && col0 >= 1024) {
        // vt epilogue: LDS transpose -> coalesced [bh][d][tok] half8 stores
        const int hh = (col0 - 1024) >> 6;
        const int bb = row0 >> 11;
        const int tok0 = row0 & 2047;
#pragma unroll
        for (int i = 0; i < 4; ++i)
#pragma unroll
            for (int j = 0; j < 2; ++j) {
                const int lc = wn + j * 16 + low;            // d within head
                float bv = bias1[hh * 64 + lc];
                half4 ph;
#pragma unroll
                for (int r = 0; r < 4; ++r) ph[r] = (_Float16)(acc[i][j][r] + bv);
                *(half4*)(&Tt[lc * 136 + wm + i * 16 + quad * 4]) = ph;
            }
        __syncthreads();
        _Float16* vb = (_Float16*)out1 + ((size_t)(bb * 16 + hh) * 64) * 2048;
#pragma unroll
        for (int it = 0; it < 4; ++it) {
            const int e = t + 256 * it;           // 1024 half8 groups
            const int d = e >> 4, tk = (e & 15) * 8;
            half8 val = *(const half8*)(&Tt[d * 136 + tk]);
            *(half8*)(vb + (size_t)d * 2048 + tok0 + tk) = val;
        }
        return;
    }

#pragma unroll
    for (int i = 0; i < 4; ++i) {
#pragma unroll
        for (int j = 0; j < 2; ++j) {
            const int col = col0 + wn + j * 16 + low;
            const int rbase = row0 + wm + i * 16 + quad * 4;
            if (MODE == 2) {
                const float bv = bias0[col];
#pragma unroll
                for (int r = 0; r < 4; ++r)
                    ((float*)out0)[(size_t)(rbase + r) * 1024 + col] = acc[i][j][r] + bv;
            } else if (col < 1024) {
                float bv = bias0[col];
#pragma unroll
                for (int r = 0; r < 4; ++r) {
                    float val = acc[i][j][r] + bv;
                    if (MODE == 0) val *= 0.125f;   // fold attention scale into q
                    ((_Float16*)out0)[(size_t)(rbase + r) * 1024 + col] = (_Float16)val;
                }
            } else {                               // MODE 0 lat region
                const int c2 = col - 1024;
                float bv = bias1[c2];
#pragma unroll
                for (int r = 0; r < 4; ++r)
                    ((_Float16*)out1)[(size_t)(rbase + r) * 256 + c2] =
                        (_Float16)(acc[i][j][r] + bv);
            }
        }
    }
}

// ---------------- flash attention v10: split-KV x2, 128 q per block ---------
// 4 waves x 32 q each. Ps[128][76] = 19 KB; total LDS 38.9 KB -> 4 blocks/CU.
__global__ __launch_bounds__(256, 4) void mla_attn(
    const _Float16* __restrict__ qp,  // [4096][1024], pre-scaled 0.125
    const _Float16* __restrict__ kk,  // [4096][1024]
    const _Float16* __restrict__ vt,  // [32][64][2048]
    _Float16* __restrict__ Op0, _Float16* __restrict__ Op1,
    float* __restrict__ lp)           // [2][32][2048]
{
    constexpr int S = 2048;
    __shared__ _Float16 Ks[64][76];    // K tile   [j][d]   9.5 KB
    __shared__ _Float16 Vs[64][76];    // V^T tile [d][j]   9.5 KB
    __shared__ _Float16 Ps[128][76];   // P tile   [i][j]  19.0 KB

    const int t = threadIdx.x, lane = t & 63, w = t >> 6;
    const int quad = lane >> 4, low = lane & 15;
    const int q0 = blockIdx.x * 128;
    const int b = blockIdx.y >> 4, h = blockIdx.y & 15;
    const int split = blockIdx.z;

    half8 qf[2][2];
#pragma unroll
    for (int ni = 0; ni < 2; ++ni)
#pragma unroll
        for (int ks = 0; ks < 2; ++ks)
            qf[ni][ks] = *(const half8*)(qp +
                (size_t)(b * S + q0 + w * 32 + ni * 16 + low) * 1024 +
                h * 64 + ks * 32 + quad * 8);

    floatx4 oa[2][4], ls[2];
    const floatx4 z4 = {0.f, 0.f, 0.f, 0.f};
#pragma unroll
    for (int mi = 0; mi < 2; ++mi) {
        ls[mi] = z4;
#pragma unroll
        for (int nd = 0; nd < 4; ++nd) oa[mi][nd] = z4;
    }

    const _Float16* kbase = kk + (size_t)(b * S) * 1024 + h * 64;
    const _Float16* vbase = vt + (size_t)(b * 16 + h) * 64 * 2048;

    const int jbeg = split * 1024, jend = jbeg + 1024;
    for (int j0 = jbeg; j0 < jend; j0 += 64) {
        __syncthreads();
#pragma unroll
        for (int p = 0; p < 2; ++p) {
            int c = p * 256 + t;
            int r = c >> 3, o8 = (c & 7) * 8;
            *(half8*)(&Ks[r][o8]) = *(const half8*)(kbase + (size_t)(j0 + r) * 1024 + o8);
            *(half8*)(&Vs[r][o8]) = *(const half8*)(vbase + (size_t)r * 2048 + j0 + o8);
        }
        __syncthreads();

        floatx4 s[4][2];
        const floatx4 i4 = {-3.f, -3.f, -3.f, -3.f};
#pragma unroll
        for (int mj = 0; mj < 4; ++mj)
#pragma unroll
            for (int ni = 0; ni < 2; ++ni) s[mj][ni] = i4;
#pragma unroll
        for (int ks = 0; ks < 2; ++ks) {
            half8 af[4];
#pragma unroll
            for (int mj = 0; mj < 4; ++mj)
                af[mj] = *(const half8*)(&Ks[mj * 16 + low][ks * 32 + quad * 8]);
#pragma unroll
            for (int mj = 0; mj < 4; ++mj)
#pragma unroll
                for (int ni = 0; ni < 2; ++ni)
                    s[mj][ni] = __builtin_amdgcn_mfma_f32_16x16x32_f16(af[mj], qf[ni][ks], s[mj][ni], 0, 0, 0);
        }

#pragma unroll
        for (int mj = 0; mj < 4; ++mj)
#pragma unroll
            for (int ni = 0; ni < 2; ++ni) {
                floatx4 pv;
#pragma unroll
                for (int r = 0; r < 4; ++r) pv[r] = __expf(s[mj][ni][r]);
                ls[ni] += pv;
                half4 ph;
#pragma unroll
                for (int r = 0; r < 4; ++r) ph[r] = (_Float16)pv[r];
                *(half4*)(&Ps[w * 32 + ni * 16 + low][mj * 16 + quad * 4]) = ph;
            }

#pragma unroll
        for (int ks = 0; ks < 2; ++ks) {
            half8 pf[2], vf[4];
#pragma unroll
            for (int mi = 0; mi < 2; ++mi)
                pf[mi] = *(const half8*)(&Ps[w * 32 + mi * 16 + low][ks * 32 + quad * 8]);
#pragma unroll
            for (int nd = 0; nd < 4; ++nd)
                vf[nd] = *(const half8*)(&Vs[nd * 16 + low][ks * 32 + quad * 8]);
#pragma unroll
            for (int mi = 0; mi < 2; ++mi)
#pragma unroll
                for (int nd = 0; nd < 4; ++nd)
                    oa[mi][nd] = __builtin_amdgcn_mfma_f32_16x16x32_f16(pf[mi], vf[nd], oa[mi][nd], 0, 0, 0);
        }
    }

#pragma unroll
    for (int ni = 0; ni < 2; ++ni) {
        float l = ls[ni][0] + ls[ni][1] + ls[ni][2] + ls[ni][3];
        l += __shfl_xor(l, 16);
        l += __shfl_xor(l, 32);
        if (quad == 0)
            lp[split * 65536 + (b * 16 + h) * 2048 + q0 + w * 32 + ni * 16 + low] = l;
    }
    _Float16* op = split ? Op1 : Op0;
#pragma unroll
    for (int mi = 0; mi < 2; ++mi)
#pragma unroll
        for (int nd = 0; nd < 4; ++nd)
#pragma unroll
            for (int r = 0; r < 4; ++r)
                op[(size_t)(b * S + q0 + w * 32 + mi * 16 + quad * 4 + r) * 1024 +
                   h * 64 + nd * 16 + low] = (_Float16)oa[mi][nd][r];
}

// ---------------- combine: att = (O0+O1)/(l0+l1) ----------------
__global__ __launch_bounds__(256) void attn_combine(
    const _Float16* __restrict__ O0, const _Float16* __restrict__ O1,
    const float* __restrict__ lp, _Float16* __restrict__ att)
{
    size_t idx = ((size_t)blockIdx.x * 256 + threadIdx.x) * 8;
    int row = (int)(idx >> 10), c = (int)(idx & 1023);
    int b = row >> 11, qq = row & 2047, h = c >> 6;
    int li = (b * 16 + h) * 2048 + qq;
    float inv = 1.f / (lp[li] + lp[65536 + li]);
    half8 a = *(const half8*)(O0 + idx);
    half8 bb = *(const half8*)(O1 + idx);
    half8 o;
#pragma unroll
    for (int r = 0; r < 8; ++r)
        o[r] = (_Float16)(((float)a[r] + (float)bb[r]) * inv);
    *(half8*)(att + idx) = o;
}

extern "C" void kernel_launch(void* const* d_in, const int* in_sizes, int n_in,
                              void* d_out, int out_size, void* d_ws, size_t ws_size,
                              hipStream_t stream) {
    const float* x  = (const float*)d_in[0];
    const float* Wq = (const float*)d_in[1];
    const float* bq = (const float*)d_in[2];
    const float* Wl = (const float*)d_in[3];
    const float* bl = (const float*)d_in[4];
    const float* Wk = (const float*)d_in[5];
    const float* bk = (const float*)d_in[6];
    const float* Wv = (const float*)d_in[7];
    const float* bv = (const float*)d_in[8];
    const float* Wo = (const float*)d_in[9];
    const float* bo = (const float*)d_in[10];
    float* out = (float*)d_out;

    // workspace carve-up (halfs), ~49.9 MB
    _Float16* p   = (_Float16*)d_ws;
    _Float16* xh  = p; p += 4194304;   // x f16; dead after GEMM1 -> Opart[1]
    _Float16* qh  = p; p += 4194304;   // q' (pre-scaled by 0.125)
    _Float16* kh  = p; p += 4194304;   // k; dead after attn -> combined att
    _Float16* vtb = p; p += 4194304;   // vt [32][64][2048]
    _Float16* ah  = p; p += 4194304;   // Opart[0]
    _Float16* lat = p; p += 1048576;   // lat; dead after GEMM2 -> lp (f32)
    _Float16* Bt1 = p; p += 1310720;
    _Float16* Bt2 = p; p += 524288;
    _Float16* Wot = p; p += 1048576;

    prep<<<dim3(32, 32, 6), 256, 0, stream>>>(x, Wq, Wl, Wk, Wv, Wo, xh, Bt1, Bt2, Wot);

    gemm_fused<0><<<dim3(20, 32), 256, 0, stream>>>(
        xh, Bt1, bq, bl, qh, lat, 1280, 1024);
    gemm_fused<1><<<dim3(32, 32), 256, 0, stream>>>(
        lat, Bt2, bk, bv, kh, vtb, 2048, 256);
    mla_attn<<<dim3(16, 32, 2), 256, 0, stream>>>(qh, kh, vtb, ah, xh, (float*)lat);
    attn_combine<<<2048, 256, 0, stream>>>(ah, xh, (const float*)lat, kh);
    gemm_fused<2><<<dim3(16, 32), 256, 0, stream>>>(
        kh, Wot, bo, nullptr, out, nullptr, 1024, 1024);
}

// Round 2
// 206.036 us; speedup vs baseline: 1.0273x; 1.0273x over previous
//
#include <hip/hip_runtime.h>

// ---------------------------------------------------------------------------
// MLA attention, fp16 MFMA pipeline v11.  B=2, S=2048, D=1024, H=16, Dh=64, L=256
//
// attn v11: LDS-pipe-bound diagnosis (v10: Occ 2x'd -> no change; DS-issue
// ~33us/CU > MFMA 16.6us/CU). Rewrite on 32x32x16 MFMA with swapped QK:
//   - P stays in registers: cvt-pack f32->f16 pairs + v_permlane32_swap_b32
//     gives the PV A-frag directly (T12). Ps LDS buffer deleted (-19KB, -24
//     DS ops/wave/tile).
//   - K/V tiles in swizzled-linear LDS [64][64]: slot=((g^(r&7))+(r>>3))&7
//     keeps rows 16B-aligned AND frag reads/writes bank-uniform (8-deep).
//   - per wave: 32q x 64j tile; 8 QK MFMA + 8 PV MFMA; 16 b128 frag reads.
//
// MFMA 32x32x16 f16 layouts (guide m74/m101, dtype-indep):
//   A-frag: lane holds A[m=lane&31][k=(lane>>5)*8+j]   B-frag symmetric
//   C/D:    lane reg r holds C[row=(r&3)+8*(r>>2)+4*(lane>>5)][col=lane&31]
// ---------------------------------------------------------------------------

typedef _Float16 half8  __attribute__((ext_vector_type(8)));
typedef _Float16 half4  __attribute__((ext_vector_type(4)));
typedef float    floatx4 __attribute__((ext_vector_type(4)));
typedef float    floatx16 __attribute__((ext_vector_type(16)));

// ---------------- prep: convert x + all weight transposes (linear) ---------
__global__ __launch_bounds__(256) void prep(
    const float* __restrict__ x,
    const float* __restrict__ Wq, const float* __restrict__ Wl,
    const float* __restrict__ Wk, const float* __restrict__ Wv,
    const float* __restrict__ Wo,
    _Float16* __restrict__ xh,
    _Float16* __restrict__ Bt1, _Float16* __restrict__ Bt2,
    _Float16* __restrict__ Wot)
{
    const int t = threadIdx.x;
    if (blockIdx.z == 5) {              // convert x: 1024 slots x 256 thr x 16
        size_t base = ((size_t)(blockIdx.y * 32 + blockIdx.x) * 256 + t) * 16;
#pragma unroll
        for (int it = 0; it < 4; ++it) {
            floatx4 v = *(const floatx4*)(x + base + it * 4);
            *(half4*)(xh + base + it * 4) = __builtin_convertvector(v, half4);
        }
        return;
    }
    const float* src; _Float16* dst; int K, N;
    switch (blockIdx.z) {
        case 0:  src = Wq; dst = Bt1;                 K = 1024; N = 1024; break;
        case 1:  src = Wl; dst = Bt1 + 1024 * 1024;   K = 1024; N = 256;  break;
        case 2:  src = Wk; dst = Bt2;                 K = 256;  N = 1024; break;
        case 3:  src = Wv; dst = Bt2 + 1024 * 256;    K = 256;  N = 1024; break;
        default: src = Wo; dst = Wot;                 K = 1024; N = 1024; break;
    }
    const int n0 = blockIdx.x * 32, k0 = blockIdx.y * 32;
    if (n0 >= N || k0 >= K) return;
    __shared__ _Float16 tile[32][33];
    const int tx = t & 31, ty = t >> 5;
#pragma unroll
    for (int i = 0; i < 4; ++i)
        tile[ty + 8 * i][tx] = (_Float16)src[(size_t)(k0 + ty + 8 * i) * N + n0 + tx];
    __syncthreads();
#pragma unroll
    for (int i = 0; i < 4; ++i)
        dst[(size_t)(n0 + ty + 8 * i) * K + k0 + tx] = tile[tx][ty + 8 * i];
}

// ---------------- fp16 MFMA GEMM, 128x64 tile, BK=64, 4 waves (64x32 each) --
// MODE 0: col<1024 -> q'=0.125*(c+bq) f16; col>=1024 -> lat f16 [*,256]
// MODE 1: col<1024 -> k f16 RM; col>=1024 -> vt[bh][d][s] via LDS transpose
// MODE 2: out f32 RM + bias
template <int MODE>
__global__ __launch_bounds__(256) void gemm_fused(
    const _Float16* __restrict__ A, const _Float16* __restrict__ Bt,
    const float* __restrict__ bias0, const float* __restrict__ bias1,
    void* __restrict__ out0, void* __restrict__ out1,
    int N, int K)
{
    __shared__ _Float16 As[128 * 64];                 // 16 KB
    __shared__ _Float16 Bs[64 * 64];                  // 8 KB
    __shared__ _Float16 Tt[(MODE == 1) ? 64 * 136 : 1];
    const int t = threadIdx.x;
    const int lane = t & 63, w = t >> 6;
    const int quad = lane >> 4, low = lane & 15;
    const int row0 = blockIdx.y * 128, col0 = blockIdx.x * 64;
    const int wm = (w >> 1) * 64, wn = (w & 1) * 32;

    floatx4 acc[4][2];
    const floatx4 z4 = {0.f, 0.f, 0.f, 0.f};
#pragma unroll
    for (int i = 0; i < 4; ++i)
#pragma unroll
        for (int j = 0; j < 2; ++j) acc[i][j] = z4;

    // BK=64 staging: one inst = 8 rows x 8 slots of 16B. Lane (srow8, sslot).
    // Lane fetches global group sslot^(row&7) so LDS slot s holds group
    // s^(row&7): frag readers un-permute with the same XOR.
    const int srow8 = lane >> 3;
    const int sslot = lane & 7;
    const int fswz = (low & 7);          // frag-read XOR term

    for (int k0 = 0; k0 < K; k0 += 64) {
        __syncthreads();
#pragma unroll
        for (int c = 0; c < 4; ++c) {      // A: 16 chunks of 8 rows, 4 per wave
            const int chunk = w * 4 + c;
            const int row = chunk * 8 + srow8;
            const int g = sslot ^ (row & 7);
            const _Float16* gp = A + (size_t)(row0 + row) * K + k0 + g * 8;
            __builtin_amdgcn_global_load_lds(
                (const __attribute__((address_space(1))) void*)gp,
                (__attribute__((address_space(3))) void*)(As + chunk * 512), 16, 0, 0);
        }
#pragma unroll
        for (int c = 0; c < 2; ++c) {      // B: 8 chunks of 8 rows, 2 per wave
            const int chunk = w * 2 + c;
            const int row = chunk * 8 + srow8;
            const int g = sslot ^ (row & 7);
            const _Float16* gp = Bt + (size_t)(col0 + row) * K + k0 + g * 8;
            __builtin_amdgcn_global_load_lds(
                (const __attribute__((address_space(1))) void*)gp,
                (__attribute__((address_space(3))) void*)(Bs + chunk * 512), 16, 0, 0);
        }
        __syncthreads();

#pragma unroll
        for (int kk = 0; kk < 2; ++kk) {
            const int slot = ((4 * kk + quad) ^ fswz) << 3;
            half8 a[4], b[2];
#pragma unroll
            for (int i = 0; i < 4; ++i)
                a[i] = *(const half8*)(As + (wm + i * 16 + low) * 64 + slot);
#pragma unroll
            for (int j = 0; j < 2; ++j)
                b[j] = *(const half8*)(Bs + (wn + j * 16 + low) * 64 + slot);
#pragma unroll
            for (int i = 0; i < 4; ++i)
#pragma unroll
                for (int j = 0; j < 2; ++j)
                    acc[i][j] = __builtin_amdgcn_mfma_f32_16x16x32_f16(a[i], b[j], acc[i][j], 0, 0, 0);
        }
    }

    if (MODE == 1 && col0 >= 1024) {
        // vt epilogue: LDS transpose -> coalesced [bh][d][tok] half8 stores
        const int hh = (col0 - 1024) >> 6;
        const int bb = row0 >> 11;
        const int tok0 = row0 & 2047;
#pragma unroll
        for (int i = 0; i < 4; ++i)
#pragma unroll
            for (int j = 0; j < 2; ++j) {
                const int lc = wn + j * 16 + low;            // d within head
                float bv = bias1[hh * 64 + lc];
                half4 ph;
#pragma unroll
                for (int r = 0; r < 4; ++r) ph[r] = (_Float16)(acc[i][j][r] + bv);
                *(half4*)(&Tt[lc * 136 + wm + i * 16 + quad * 4]) = ph;
            }
        __syncthreads();
        _Float16* vb = (_Float16*)out1 + ((size_t)(bb * 16 + hh) * 64) * 2048;
#pragma unroll
        for (int it = 0; it < 4; ++it) {
            const int e = t + 256 * it;           // 1024 half8 groups
            const int d = e >> 4, tk = (e & 15) * 8;
            half8 val = *(const half8*)(&Tt[d * 136 + tk]);
            *(half8*)(vb + (size_t)d * 2048 + tok0 + tk) = val;
        }
        return;
    }

#pragma unroll
    for (int i = 0; i < 4; ++i) {
#pragma unroll
        for (int j = 0; j < 2; ++j) {
            const int col = col0 + wn + j * 16 + low;
            const int rbase = row0 + wm + i * 16 + quad * 4;
            if (MODE == 2) {
                const float bv = bias0[col];
#pragma unroll
                for (int r = 0; r < 4; ++r)
                    ((float*)out0)[(size_t)(rbase + r) * 1024 + col] = acc[i][j][r] + bv;
            } else if (col < 1024) {
                float bv = bias0[col];
#pragma unroll
                for (int r = 0; r < 4; ++r) {
                    float val = acc[i][j][r] + bv;
                    if (MODE == 0) val *= 0.125f;   // fold attention scale into q
                    ((_Float16*)out0)[(size_t)(rbase + r) * 1024 + col] = (_Float16)val;
                }
            } else {                               // MODE 0 lat region
                const int c2 = col - 1024;
                float bv = bias1[c2];
#pragma unroll
                for (int r = 0; r < 4; ++r)
                    ((_Float16*)out1)[(size_t)(rbase + r) * 256 + c2] =
                        (_Float16)(acc[i][j][r] + bv);
            }
        }
    }
}

// f32 pair -> packed f16x2 (RNE via scalar cvts; compiler emits cvt+pack)
__device__ __forceinline__ unsigned pk2(float a, float b) {
    union { _Float16 h[2]; unsigned u; } x;
    x.h[0] = (_Float16)a; x.h[1] = (_Float16)b; return x.u;
}

// ---------------- flash attention v11: 32x32 MFMA, in-register P -----------
// 4 waves x 32q, j-tile 64, split-KV x2. LDS: Ks+Vs 16KB, swizzled-linear.
__global__ __launch_bounds__(256) void mla_attn(
    const _Float16* __restrict__ qp,  // [4096][1024], pre-scaled 0.125
    const _Float16* __restrict__ kk,  // [4096][1024]
    const _Float16* __restrict__ vt,  // [32][64][2048]
    _Float16* __restrict__ Op0, _Float16* __restrict__ Op1,
    float* __restrict__ lp)           // [2][32][2048]
{
    constexpr int S = 2048;
    // swizzled-linear [row][slot]: halfs, slot(row,g) = ((g^(row&7))+(row>>3))&7
    __shared__ _Float16 Ks[64 * 64];   // [j][d]  8 KB
    __shared__ _Float16 Vs[64 * 64];   // [d][j]  8 KB

    const int t = threadIdx.x, lane = t & 63, w = t >> 6;
    const int l31 = lane & 31, hi = lane >> 5;
    const int rho = l31 & 7, sig = l31 >> 3;
    const int q0 = blockIdx.x * 128;
    const int b = blockIdx.y >> 4, h = blockIdx.y & 15;
    const int split = blockIdx.z;

    // Q frag (B-operand): B[n=q=l31][k = ks*16 + hi*8 + j]
    half8 qf[4];
#pragma unroll
    for (int ks = 0; ks < 4; ++ks)
        qf[ks] = *(const half8*)(qp +
            (size_t)(b * S + q0 + w * 32 + l31) * 1024 + h * 64 + ks * 16 + hi * 8);

    floatx16 oa[2];
#pragma unroll
    for (int nd = 0; nd < 2; ++nd)
#pragma unroll
        for (int r = 0; r < 16; ++r) oa[nd][r] = 0.f;
    float ls = 0.f;

    const _Float16* kbase = kk + (size_t)(b * S) * 1024 + h * 64;
    const _Float16* vbase = vt + (size_t)(b * 16 + h) * 64 * 2048;

    const int jbeg = split * 1024, jend = jbeg + 1024;
    for (int j0 = jbeg; j0 < jend; j0 += 64) {
        __syncthreads();
#pragma unroll
        for (int p = 0; p < 2; ++p) {       // 512 groups each for K and V
            const int c = p * 256 + t;
            const int r = c >> 3, g = c & 7;
            const int s8 = ((g ^ (r & 7)) + (r >> 3)) & 7;
            *(half8*)(Ks + r * 64 + s8 * 8) =
                *(const half8*)(kbase + (size_t)(j0 + r) * 1024 + g * 8);
            *(half8*)(Vs + r * 64 + s8 * 8) =
                *(const half8*)(vbase + (size_t)r * 2048 + j0 + g * 8);
        }
        __syncthreads();

        // QK^T swapped: sc[jb] = K(32j) . Q(32q), K-dim 64 in 4 steps
        floatx16 sc[2];
#pragma unroll
        for (int jb = 0; jb < 2; ++jb)
#pragma unroll
            for (int r = 0; r < 16; ++r) sc[jb][r] = -3.f;   // fixed-shift guard

#pragma unroll
        for (int jb = 0; jb < 2; ++jb)
#pragma unroll
            for (int ks = 0; ks < 4; ++ks) {
                const int row = jb * 32 + l31;
                const int s8 = (((2 * ks + hi) ^ rho) + sig + 4 * jb) & 7;
                half8 kf = *(const half8*)(Ks + row * 64 + s8 * 8);
                sc[jb] = __builtin_amdgcn_mfma_f32_32x32x16_f16(kf, qf[ks], sc[jb], 0, 0, 0);
            }

        // softmax (fixed shift) + in-register P transpose -> PV A-frags
        half8 pfrag[2][2];
#pragma unroll
        for (int jb = 0; jb < 2; ++jb) {
#pragma unroll
            for (int r = 0; r < 16; ++r) {
                sc[jb][r] = __expf(sc[jb][r]);
                ls += sc[jb][r];
            }
#pragma unroll
            for (int kb = 0; kb < 2; ++kb) {
                unsigned a0 = pk2(sc[jb][8 * kb + 0], sc[jb][8 * kb + 1]);
                unsigned a1 = pk2(sc[jb][8 * kb + 2], sc[jb][8 * kb + 3]);
                unsigned b0 = pk2(sc[jb][8 * kb + 4], sc[jb][8 * kb + 5]);
                unsigned b1 = pk2(sc[jb][8 * kb + 6], sc[jb][8 * kb + 7]);
                asm("v_permlane32_swap_b32 %0, %1" : "+v"(a0), "+v"(b0));
                asm("v_permlane32_swap_b32 %0, %1" : "+v"(a1), "+v"(b1));
                union { unsigned u[4]; half8 h; } pu;
                pu.u[0] = a0; pu.u[1] = a1; pu.u[2] = b0; pu.u[3] = b1;
                pfrag[jb][kb] = pu.h;       // A[m=q=l31][k=hi*8+j], j-step kb
            }
        }

        // PV: oa[nd] += P(32q x 16j) . V(16j x 32d), 4 j-steps x 2 d-tiles
#pragma unroll
        for (int jb = 0; jb < 2; ++jb)
#pragma unroll
            for (int kb = 0; kb < 2; ++kb)
#pragma unroll
                for (int nd = 0; nd < 2; ++nd) {
                    const int row = nd * 32 + l31;
                    const int g = 4 * jb + 2 * kb + hi;
                    const int s8 = ((g ^ rho) + sig + 4 * nd) & 7;
                    half8 vf = *(const half8*)(Vs + row * 64 + s8 * 8);
                    oa[nd] = __builtin_amdgcn_mfma_f32_32x32x16_f16(pfrag[jb][kb], vf, oa[nd], 0, 0, 0);
                }
    }

    // l: lane holds partial over its C-rows; partner (lane^32) has the rest
    float l2 = ls + __shfl_xor(ls, 32);
    if (hi == 0)
        lp[split * 65536 + (b * 16 + h) * 2048 + q0 + w * 32 + l31] = l2;

    _Float16* op = split ? Op1 : Op0;
#pragma unroll
    for (int nd = 0; nd < 2; ++nd)
#pragma unroll
        for (int r = 0; r < 16; ++r) {
            const int qrow = (r & 3) + 8 * (r >> 2) + 4 * hi;
            op[(size_t)(b * S + q0 + w * 32 + qrow) * 1024 +
               h * 64 + nd * 32 + l31] = (_Float16)oa[nd][r];
        }
}

// ---------------- combine: att = (O0+O1)/(l0+l1) ----------------
__global__ __launch_bounds__(256) void attn_combine(
    const _Float16* __restrict__ O0, const _Float16* __restrict__ O1,
    const float* __restrict__ lp, _Float16* __restrict__ att)
{
    size_t idx = ((size_t)blockIdx.x * 256 + threadIdx.x) * 8;
    int row = (int)(idx >> 10), c = (int)(idx & 1023);
    int b = row >> 11, qq = row & 2047, h = c >> 6;
    int li = (b * 16 + h) * 2048 + qq;
    float inv = 1.f / (lp[li] + lp[65536 + li]);
    half8 a = *(const half8*)(O0 + idx);
    half8 bb = *(const half8*)(O1 + idx);
    half8 o;
#pragma unroll
    for (int r = 0; r < 8; ++r)
        o[r] = (_Float16)(((float)a[r] + (float)bb[r]) * inv);
    *(half8*)(att + idx) = o;
}

extern "C" void kernel_launch(void* const* d_in, const int* in_sizes, int n_in,
                              void* d_out, int out_size, void* d_ws, size_t ws_size,
                              hipStream_t stream) {
    const float* x  = (const float*)d_in[0];
    const float* Wq = (const float*)d_in[1];
    const float* bq = (const float*)d_in[2];
    const float* Wl = (const float*)d_in[3];
    const float* bl = (const float*)d_in[4];
    const float* Wk = (const float*)d_in[5];
    const float* bk = (const float*)d_in[6];
    const float* Wv = (const float*)d_in[7];
    const float* bv = (const float*)d_in[8];
    const float* Wo = (const float*)d_in[9];
    const float* bo = (const float*)d_in[10];
    float* out = (float*)d_out;

    // workspace carve-up (halfs), ~49.9 MB
    _Float16* p   = (_Float16*)d_ws;
    _Float16* xh  = p; p += 4194304;   // x f16; dead after GEMM1 -> Opart[1]
    _Float16* qh  = p; p += 4194304;   // q' (pre-scaled by 0.125)
    _Float16* kh  = p; p += 4194304;   // k; dead after attn -> combined att
    _Float16* vtb = p; p += 4194304;   // vt [32][64][2048]
    _Float16* ah  = p; p += 4194304;   // Opart[0]
    _Float16* lat = p; p += 1048576;   // lat; dead after GEMM2 -> lp (f32)
    _Float16* Bt1 = p; p += 1310720;
    _Float16* Bt2 = p; p += 524288;
    _Float16* Wot = p; p += 1048576;

    prep<<<dim3(32, 32, 6), 256, 0, stream>>>(x, Wq, Wl, Wk, Wv, Wo, xh, Bt1, Bt2, Wot);

    gemm_fused<0><<<dim3(20, 32), 256, 0, stream>>>(
        xh, Bt1, bq, bl, qh, lat, 1280, 1024);
    gemm_fused<1><<<dim3(32, 32), 256, 0, stream>>>(
        lat, Bt2, bk, bv, kh, vtb, 2048, 256);
    mla_attn<<<dim3(16, 32, 2), 256, 0, stream>>>(qh, kh, vtb, ah, xh, (float*)lat);
    attn_combine<<<2048, 256, 0, stream>>>(ah, xh, (const float*)lat, kh);
    gemm_fused<2><<<dim3(16, 32), 256, 0, stream>>>(
        kh, Wot, bo, nullptr, out, nullptr, 1024, 1024);
}

// Round 4
// 204.475 us; speedup vs baseline: 1.0352x; 1.0076x over previous
//
#include <hip/hip_runtime.h>

// ---------------------------------------------------------------------------
// MLA attention, fp16 MFMA pipeline v12b.  B=2, S=2048, D=1024, H=16, Dh=64, L=256
//
// attn v12 (from v11 post-mortem):
//   - v11's [64][64] XOR-swizzle LDS was a 4-way bank conflict by construction
//     (row stride 128B = 32 banks -> row drops out of bank eq; 32 lanes onto
//     8 slots). SQ_LDS_BANK_CONFLICT 4.19M. Revert to v10-proven padded
//     [64][76] (stride 152B = 38 banks, rotation 6, gcd 2 -> worst 2-way=free).
//   - softmax VALU trim: q pre-scaled by 0.125*log2e in GEMM1 -> bare v_exp_f32
//     (exp2); cvt_pkrtz single-instr pack replaces cvt+cvt+pack. Fixed shift
//     now 2^-4 (cancels in combine).
//   - s_setprio(1) around QK and PV MFMA clusters (T5, attn-proven).
//   - keeps v11's in-register P transpose (32x32 MFMA, permlane32_swap).
// v12b: fix pk2 union type (__fp16 ext_vector(2), the builtin's return type).
//
// MFMA 32x32x16 f16 layouts (guide m74/m101, dtype-indep):
//   A-frag: lane holds A[m=lane&31][k=(lane>>5)*8+j]   B-frag symmetric
//   C/D:    lane reg r holds C[row=(r&3)+8*(r>>2)+4*(lane>>5)][col=lane&31]
// ---------------------------------------------------------------------------

typedef _Float16 half8  __attribute__((ext_vector_type(8)));
typedef _Float16 half4  __attribute__((ext_vector_type(4)));
typedef __fp16   fp16x2 __attribute__((ext_vector_type(2)));
typedef float    floatx4 __attribute__((ext_vector_type(4)));
typedef float    floatx16 __attribute__((ext_vector_type(16)));

#if __has_builtin(__builtin_amdgcn_exp2f)
#define EXP2F(x) __builtin_amdgcn_exp2f(x)
#else
#define EXP2F(x) exp2f(x)
#endif

// ---------------- prep: convert x + all weight transposes (linear) ---------
__global__ __launch_bounds__(256) void prep(
    const float* __restrict__ x,
    const float* __restrict__ Wq, const float* __restrict__ Wl,
    const float* __restrict__ Wk, const float* __restrict__ Wv,
    const float* __restrict__ Wo,
    _Float16* __restrict__ xh,
    _Float16* __restrict__ Bt1, _Float16* __restrict__ Bt2,
    _Float16* __restrict__ Wot)
{
    const int t = threadIdx.x;
    if (blockIdx.z == 5) {              // convert x: 1024 slots x 256 thr x 16
        size_t base = ((size_t)(blockIdx.y * 32 + blockIdx.x) * 256 + t) * 16;
#pragma unroll
        for (int it = 0; it < 4; ++it) {
            floatx4 v = *(const floatx4*)(x + base + it * 4);
            *(half4*)(xh + base + it * 4) = __builtin_convertvector(v, half4);
        }
        return;
    }
    const float* src; _Float16* dst; int K, N;
    switch (blockIdx.z) {
        case 0:  src = Wq; dst = Bt1;                 K = 1024; N = 1024; break;
        case 1:  src = Wl; dst = Bt1 + 1024 * 1024;   K = 1024; N = 256;  break;
        case 2:  src = Wk; dst = Bt2;                 K = 256;  N = 1024; break;
        case 3:  src = Wv; dst = Bt2 + 1024 * 256;    K = 256;  N = 1024; break;
        default: src = Wo; dst = Wot;                 K = 1024; N = 1024; break;
    }
    const int n0 = blockIdx.x * 32, k0 = blockIdx.y * 32;
    if (n0 >= N || k0 >= K) return;
    __shared__ _Float16 tile[32][33];
    const int tx = t & 31, ty = t >> 5;
#pragma unroll
    for (int i = 0; i < 4; ++i)
        tile[ty + 8 * i][tx] = (_Float16)src[(size_t)(k0 + ty + 8 * i) * N + n0 + tx];
    __syncthreads();
#pragma unroll
    for (int i = 0; i < 4; ++i)
        dst[(size_t)(n0 + ty + 8 * i) * K + k0 + tx] = tile[tx][ty + 8 * i];
}

// ---------------- fp16 MFMA GEMM, 128x64 tile, BK=64, 4 waves (64x32 each) --
// MODE 0: col<1024 -> q'=0.18034*(c+bq) f16 (0.125*log2e, feeds exp2-softmax);
//         col>=1024 -> lat f16 [*,256]
// MODE 1: col<1024 -> k f16 RM; col>=1024 -> vt[bh][d][s] via LDS transpose
// MODE 2: out f32 RM + bias
template <int MODE>
__global__ __launch_bounds__(256) void gemm_fused(
    const _Float16* __restrict__ A, const _Float16* __restrict__ Bt,
    const float* __restrict__ bias0, const float* __restrict__ bias1,
    void* __restrict__ out0, void* __restrict__ out1,
    int N, int K)
{
    __shared__ _Float16 As[128 * 64];                 // 16 KB
    __shared__ _Float16 Bs[64 * 64];                  // 8 KB
    __shared__ _Float16 Tt[(MODE == 1) ? 64 * 136 : 1];
    const int t = threadIdx.x;
    const int lane = t & 63, w = t >> 6;
    const int quad = lane >> 4, low = lane & 15;
    const int row0 = blockIdx.y * 128, col0 = blockIdx.x * 64;
    const int wm = (w >> 1) * 64, wn = (w & 1) * 32;

    floatx4 acc[4][2];
    const floatx4 z4 = {0.f, 0.f, 0.f, 0.f};
#pragma unroll
    for (int i = 0; i < 4; ++i)
#pragma unroll
        for (int j = 0; j < 2; ++j) acc[i][j] = z4;

    // BK=64 staging: one inst = 8 rows x 8 slots of 16B. Lane (srow8, sslot).
    // Lane fetches global group sslot^(row&7) so LDS slot s holds group
    // s^(row&7): frag readers un-permute with the same XOR.
    const int srow8 = lane >> 3;
    const int sslot = lane & 7;
    const int fswz = (low & 7);          // frag-read XOR term

    for (int k0 = 0; k0 < K; k0 += 64) {
        __syncthreads();
#pragma unroll
        for (int c = 0; c < 4; ++c) {      // A: 16 chunks of 8 rows, 4 per wave
            const int chunk = w * 4 + c;
            const int row = chunk * 8 + srow8;
            const int g = sslot ^ (row & 7);
            const _Float16* gp = A + (size_t)(row0 + row) * K + k0 + g * 8;
            __builtin_amdgcn_global_load_lds(
                (const __attribute__((address_space(1))) void*)gp,
                (__attribute__((address_space(3))) void*)(As + chunk * 512), 16, 0, 0);
        }
#pragma unroll
        for (int c = 0; c < 2; ++c) {      // B: 8 chunks of 8 rows, 2 per wave
            const int chunk = w * 2 + c;
            const int row = chunk * 8 + srow8;
            const int g = sslot ^ (row & 7);
            const _Float16* gp = Bt + (size_t)(col0 + row) * K + k0 + g * 8;
            __builtin_amdgcn_global_load_lds(
                (const __attribute__((address_space(1))) void*)gp,
                (__attribute__((address_space(3))) void*)(Bs + chunk * 512), 16, 0, 0);
        }
        __syncthreads();

#pragma unroll
        for (int kk = 0; kk < 2; ++kk) {
            const int slot = ((4 * kk + quad) ^ fswz) << 3;
            half8 a[4], b[2];
#pragma unroll
            for (int i = 0; i < 4; ++i)
                a[i] = *(const half8*)(As + (wm + i * 16 + low) * 64 + slot);
#pragma unroll
            for (int j = 0; j < 2; ++j)
                b[j] = *(const half8*)(Bs + (wn + j * 16 + low) * 64 + slot);
#pragma unroll
            for (int i = 0; i < 4; ++i)
#pragma unroll
                for (int j = 0; j < 2; ++j)
                    acc[i][j] = __builtin_amdgcn_mfma_f32_16x16x32_f16(a[i], b[j], acc[i][j], 0, 0, 0);
        }
    }

    if (MODE == 1 && col0 >= 1024) {
        // vt epilogue: LDS transpose -> coalesced [bh][d][tok] half8 stores
        const int hh = (col0 - 1024) >> 6;
        const int bb = row0 >> 11;
        const int tok0 = row0 & 2047;
#pragma unroll
        for (int i = 0; i < 4; ++i)
#pragma unroll
            for (int j = 0; j < 2; ++j) {
                const int lc = wn + j * 16 + low;            // d within head
                float bv = bias1[hh * 64 + lc];
                half4 ph;
#pragma unroll
                for (int r = 0; r < 4; ++r) ph[r] = (_Float16)(acc[i][j][r] + bv);
                *(half4*)(&Tt[lc * 136 + wm + i * 16 + quad * 4]) = ph;
            }
        __syncthreads();
        _Float16* vb = (_Float16*)out1 + ((size_t)(bb * 16 + hh) * 64) * 2048;
#pragma unroll
        for (int it = 0; it < 4; ++it) {
            const int e = t + 256 * it;           // 1024 half8 groups
            const int d = e >> 4, tk = (e & 15) * 8;
            half8 val = *(const half8*)(&Tt[d * 136 + tk]);
            *(half8*)(vb + (size_t)d * 2048 + tok0 + tk) = val;
        }
        return;
    }

#pragma unroll
    for (int i = 0; i < 4; ++i) {
#pragma unroll
        for (int j = 0; j < 2; ++j) {
            const int col = col0 + wn + j * 16 + low;
            const int rbase = row0 + wm + i * 16 + quad * 4;
            if (MODE == 2) {
                const float bv = bias0[col];
#pragma unroll
                for (int r = 0; r < 4; ++r)
                    ((float*)out0)[(size_t)(rbase + r) * 1024 + col] = acc[i][j][r] + bv;
            } else if (col < 1024) {
                float bv = bias0[col];
#pragma unroll
                for (int r = 0; r < 4; ++r) {
                    float val = acc[i][j][r] + bv;
                    if (MODE == 0) val *= 0.180336880f;  // 0.125 * log2(e): scale + exp2 fold
                    ((_Float16*)out0)[(size_t)(rbase + r) * 1024 + col] = (_Float16)val;
                }
            } else {                               // MODE 0 lat region
                const int c2 = col - 1024;
                float bv = bias1[c2];
#pragma unroll
                for (int r = 0; r < 4; ++r)
                    ((_Float16*)out1)[(size_t)(rbase + r) * 256 + c2] =
                        (_Float16)(acc[i][j][r] + bv);
            }
        }
    }
}

// f32 pair -> packed f16x2, single v_cvt_pkrtz_f16_f32
__device__ __forceinline__ unsigned pk2(float a, float b) {
    union { fp16x2 h; unsigned u; } x;
    x.h = __builtin_amdgcn_cvt_pkrtz(a, b);
    return x.u;
}

// ---------------- flash attention v12: 32x32 MFMA, in-register P -----------
// 4 waves x 32q, j-tile 64, split-KV x2. LDS: Ks+Vs padded [64][76], 19 KB.
__global__ __launch_bounds__(256) void mla_attn(
    const _Float16* __restrict__ qp,  // [4096][1024], pre-scaled 0.125*log2e
    const _Float16* __restrict__ kk,  // [4096][1024]
    const _Float16* __restrict__ vt,  // [32][64][2048]
    _Float16* __restrict__ Op0, _Float16* __restrict__ Op1,
    float* __restrict__ lp)           // [2][32][2048]
{
    constexpr int S = 2048;
    // padded rows: stride 76 halfs = 152B = 38 banks -> row rotation 6,
    // gcd(6,32)=2 -> worst 2-way aliasing (free, m136). v10-measured 0 conflicts.
    __shared__ _Float16 Ks[64][76];    // [j][d]  9.5 KB
    __shared__ _Float16 Vs[64][76];    // [d][j]  9.5 KB

    const int t = threadIdx.x, lane = t & 63, w = t >> 6;
    const int l31 = lane & 31, hi = lane >> 5;
    const int q0 = blockIdx.x * 128;
    const int b = blockIdx.y >> 4, h = blockIdx.y & 15;
    const int split = blockIdx.z;

    // Q frag (B-operand): B[n=q=l31][k = ks*16 + hi*8 + j]
    half8 qf[4];
#pragma unroll
    for (int ks = 0; ks < 4; ++ks)
        qf[ks] = *(const half8*)(qp +
            (size_t)(b * S + q0 + w * 32 + l31) * 1024 + h * 64 + ks * 16 + hi * 8);

    floatx16 oa[2];
#pragma unroll
    for (int nd = 0; nd < 2; ++nd)
#pragma unroll
        for (int r = 0; r < 16; ++r) oa[nd][r] = 0.f;
    float ls = 0.f;

    const _Float16* kbase = kk + (size_t)(b * S) * 1024 + h * 64;
    const _Float16* vbase = vt + (size_t)(b * 16 + h) * 64 * 2048;

    const int jbeg = split * 1024, jend = jbeg + 1024;
    for (int j0 = jbeg; j0 < jend; j0 += 64) {
        __syncthreads();
#pragma unroll
        for (int p = 0; p < 2; ++p) {       // 512 half8 groups each for K and V
            const int c = p * 256 + t;
            const int r = c >> 3, g = c & 7;
            *(half8*)(&Ks[r][g * 8]) =
                *(const half8*)(kbase + (size_t)(j0 + r) * 1024 + g * 8);
            *(half8*)(&Vs[r][g * 8]) =
                *(const half8*)(vbase + (size_t)r * 2048 + j0 + g * 8);
        }
        __syncthreads();

        // QK^T swapped: sc[jb] = K(32j) . Q(32q), K-dim 64 in 4 steps
        floatx16 sc[2];
#pragma unroll
        for (int jb = 0; jb < 2; ++jb)
#pragma unroll
            for (int r = 0; r < 16; ++r) sc[jb][r] = -4.f;   // 2^-4 fixed-shift guard

        __builtin_amdgcn_s_setprio(1);
#pragma unroll
        for (int jb = 0; jb < 2; ++jb)
#pragma unroll
            for (int ks = 0; ks < 4; ++ks) {
                half8 kf = *(const half8*)(&Ks[jb * 32 + l31][ks * 16 + hi * 8]);
                sc[jb] = __builtin_amdgcn_mfma_f32_32x32x16_f16(kf, qf[ks], sc[jb], 0, 0, 0);
            }
        __builtin_amdgcn_s_setprio(0);

        // softmax (fixed shift, base-2) + in-register P transpose -> PV A-frags
        half8 pfrag[2][2];
#pragma unroll
        for (int jb = 0; jb < 2; ++jb) {
#pragma unroll
            for (int r = 0; r < 16; ++r) {
                sc[jb][r] = EXP2F(sc[jb][r]);
                ls += sc[jb][r];
            }
#pragma unroll
            for (int kb = 0; kb < 2; ++kb) {
                unsigned a0 = pk2(sc[jb][8 * kb + 0], sc[jb][8 * kb + 1]);
                unsigned a1 = pk2(sc[jb][8 * kb + 2], sc[jb][8 * kb + 3]);
                unsigned b0 = pk2(sc[jb][8 * kb + 4], sc[jb][8 * kb + 5]);
                unsigned b1 = pk2(sc[jb][8 * kb + 6], sc[jb][8 * kb + 7]);
                asm("v_permlane32_swap_b32 %0, %1" : "+v"(a0), "+v"(b0));
                asm("v_permlane32_swap_b32 %0, %1" : "+v"(a1), "+v"(b1));
                union { unsigned u[4]; half8 h; } pu;
                pu.u[0] = a0; pu.u[1] = a1; pu.u[2] = b0; pu.u[3] = b1;
                pfrag[jb][kb] = pu.h;       // A[m=q=l31][k=hi*8+j], j-step kb
            }
        }

        // PV: oa[nd] += P(32q x 16j) . V(16j x 32d), 4 j-steps x 2 d-tiles
        __builtin_amdgcn_s_setprio(1);
#pragma unroll
        for (int jb = 0; jb < 2; ++jb)
#pragma unroll
            for (int kb = 0; kb < 2; ++kb)
#pragma unroll
                for (int nd = 0; nd < 2; ++nd) {
                    half8 vf = *(const half8*)(
                        &Vs[nd * 32 + l31][jb * 32 + kb * 16 + hi * 8]);
                    oa[nd] = __builtin_amdgcn_mfma_f32_32x32x16_f16(pfrag[jb][kb], vf, oa[nd], 0, 0, 0);
                }
        __builtin_amdgcn_s_setprio(0);
    }

    // l: lane holds partial over its C-rows; partner (lane^32) has the rest
    float l2 = ls + __shfl_xor(ls, 32);
    if (hi == 0)
        lp[split * 65536 + (b * 16 + h) * 2048 + q0 + w * 32 + l31] = l2;

    _Float16* op = split ? Op1 : Op0;
#pragma unroll
    for (int nd = 0; nd < 2; ++nd)
#pragma unroll
        for (int r = 0; r < 16; ++r) {
            const int qrow = (r & 3) + 8 * (r >> 2) + 4 * hi;
            op[(size_t)(b * S + q0 + w * 32 + qrow) * 1024 +
               h * 64 + nd * 32 + l31] = (_Float16)oa[nd][r];
        }
}

// ---------------- combine: att = (O0+O1)/(l0+l1) ----------------
__global__ __launch_bounds__(256) void attn_combine(
    const _Float16* __restrict__ O0, const _Float16* __restrict__ O1,
    const float* __restrict__ lp, _Float16* __restrict__ att)
{
    size_t idx = ((size_t)blockIdx.x * 256 + threadIdx.x) * 8;
    int row = (int)(idx >> 10), c = (int)(idx & 1023);
    int b = row >> 11, qq = row & 2047, h = c >> 6;
    int li = (b * 16 + h) * 2048 + qq;
    float inv = 1.f / (lp[li] + lp[65536 + li]);
    half8 a = *(const half8*)(O0 + idx);
    half8 bb = *(const half8*)(O1 + idx);
    half8 o;
#pragma unroll
    for (int r = 0; r < 8; ++r)
        o[r] = (_Float16)(((float)a[r] + (float)bb[r]) * inv);
    *(half8*)(att + idx) = o;
}

extern "C" void kernel_launch(void* const* d_in, const int* in_sizes, int n_in,
                              void* d_out, int out_size, void* d_ws, size_t ws_size,
                              hipStream_t stream) {
    const float* x  = (const float*)d_in[0];
    const float* Wq = (const float*)d_in[1];
    const float* bq = (const float*)d_in[2];
    const float* Wl = (const float*)d_in[3];
    const float* bl = (const float*)d_in[4];
    const float* Wk = (const float*)d_in[5];
    const float* bk = (const float*)d_in[6];
    const float* Wv = (const float*)d_in[7];
    const float* bv = (const float*)d_in[8];
    const float* Wo = (const float*)d_in[9];
    const float* bo = (const float*)d_in[10];
    float* out = (float*)d_out;

    // workspace carve-up (halfs), ~49.9 MB
    _Float16* p   = (_Float16*)d_ws;
    _Float16* xh  = p; p += 4194304;   // x f16; dead after GEMM1 -> Opart[1]
    _Float16* qh  = p; p += 4194304;   // q' (pre-scaled by 0.125*log2e)
    _Float16* kh  = p; p += 4194304;   // k; dead after attn -> combined att
    _Float16* vtb = p; p += 4194304;   // vt [32][64][2048]
    _Float16* ah  = p; p += 4194304;   // Opart[0]
    _Float16* lat = p; p += 1048576;   // lat; dead after GEMM2 -> lp (f32)
    _Float16* Bt1 = p; p += 1310720;
    _Float16* Bt2 = p; p += 524288;
    _Float16* Wot = p; p += 1048576;

    prep<<<dim3(32, 32, 6), 256, 0, stream>>>(x, Wq, Wl, Wk, Wv, Wo, xh, Bt1, Bt2, Wot);

    gemm_fused<0><<<dim3(20, 32), 256, 0, stream>>>(
        xh, Bt1, bq, bl, qh, lat, 1280, 1024);
    gemm_fused<1><<<dim3(32, 32), 256, 0, stream>>>(
        lat, Bt2, bk, bv, kh, vtb, 2048, 256);
    mla_attn<<<dim3(16, 32, 2), 256, 0, stream>>>(qh, kh, vtb, ah, xh, (float*)lat);
    attn_combine<<<2048, 256, 0, stream>>>(ah, xh, (const float*)lat, kh);
    gemm_fused<2><<<dim3(16, 32), 256, 0, stream>>>(
        kh, Wot, bo, nullptr, out, nullptr, 1024, 1024);
}